// Round 4
// baseline (1388.463 us; speedup 1.0000x reference)
//
#include <hip/hip_runtime.h>
#include <math.h>

constexpr int B = 8, C = 64, H = 256, W = 256, HWc = H * W, N = 10;

typedef short bf8 __attribute__((ext_vector_type(8)));    // 8 x bf16 (4 VGPR)
typedef float f4  __attribute__((ext_vector_type(4)));    // MFMA accum
typedef unsigned short ushort;

__device__ __forceinline__ ushort f2bf(float f) {
  unsigned u = __builtin_bit_cast(unsigned, f);
  unsigned r = (u + 0x7fffu + ((u >> 16) & 1u)) >> 16;
  return (ushort)r;
}
__device__ __forceinline__ float bf2f(ushort h) {
  unsigned u = ((unsigned)h) << 16;
  return __builtin_bit_cast(float, u);
}

// ---------------- LayerNorm: NCHW fp32 -> NHWC bf16 ----------------
__global__ __launch_bounds__(256) void ln_k(
    const float* __restrict__ x, const float* __restrict__ g,
    const float* __restrict__ bt, ushort* __restrict__ xn) {
  int pix = blockIdx.x * 256 + threadIdx.x;
  int b = blockIdx.y;
  const float* xp = x + (size_t)b * C * HWc + pix;
  float v[64];
  float s = 0.f, s2 = 0.f;
#pragma unroll
  for (int c = 0; c < 64; c++) {
    v[c] = xp[(size_t)c * HWc];
    s += v[c]; s2 += v[c] * v[c];
  }
  float mu = s * (1.f / 64);
  float var = s2 * (1.f / 64) - mu * mu;
  float rstd = rsqrtf(var + 1e-5f);
  ushort* op = xn + ((size_t)b * HWc + pix) * 64;
#pragma unroll
  for (int ch = 0; ch < 8; ch++) {
    union { ushort us[8]; int4 v4; } pk;
#pragma unroll
    for (int j = 0; j < 8; j++) {
      int c = ch * 8 + j;
      pk.us[j] = f2bf((v[c] - mu) * rstd * g[c] + bt[c]);
    }
    *reinterpret_cast<int4*>(op + ch * 8) = pk.v4;
  }
}

// ---------------- weight prep: OIHW fp32 -> MFMA fragment layout bf16 ----------------
// frags[conv][((s*4+cf)*64+lane)*8+j] = w[co][ci][tap]
//   co = cf*16 + (lane&15); tap = s>>1; ci = (s&1)*32 + (lane>>4)*8 + j
__global__ void prep_w(const float* __restrict__ w3, const float* __restrict__ wu,
                       const float* __restrict__ wd, ushort* __restrict__ frags) {
  int idx = blockIdx.x * 256 + threadIdx.x;
  if (idx >= 3 * 4608) return;
  int conv = idx / 4608, r = idx % 4608;
  int s = r >> 8, cf = (r >> 6) & 3, lane = r & 63;
  const float* w = (conv == 0) ? w3 : (conv == 1) ? wu : wd;
  int co = (cf << 4) + (lane & 15);
  int tap = s >> 1;
  ushort* o = frags + conv * 36864 + ((size_t)r) * 8;
#pragma unroll
  for (int j = 0; j < 8; j++) {
    int ci = ((s & 1) << 5) + ((lane >> 4) << 3) + j;
    o[j] = f2bf(w[(co * 64 + ci) * 9 + tap]);
  }
}

// ---------------- MFMA implicit-GEMM 3x3 conv ----------------
// in: NHWC bf16. OM=0: out NHWC bf16 (+GELU if ACT). OM=1: out NCHW fp32 + residual.
// Wave w owns co group [16w,16w+16); weights preloaded to 18 bf8 regs.
template <int ACT, int OM>
__global__ __launch_bounds__(256, 2) void conv_mfma(
    const ushort* __restrict__ in, const ushort* __restrict__ wfrag,
    const float* __restrict__ bias, const float* __restrict__ resid,
    ushort* __restrict__ outb, float* __restrict__ outf) {
  __shared__ char lds[18 * 18 * 128];  // 41472 B (epilogue reuses 32 KB of it)
  int tid = threadIdx.x;
  int b = blockIdx.z;
  int h0 = blockIdx.y * 16, w0 = blockIdx.x * 16;
  int wave = tid >> 6, lane = tid & 63;
  int lm = lane & 15, lk = lane >> 4;

  // preload all 18 weight B-frags for this wave's co group
  const bf8* wf = reinterpret_cast<const bf8*>(wfrag);
  bf8 wb[18];
#pragma unroll
  for (int s = 0; s < 18; s++) wb[s] = wf[(s * 4 + wave) * 64 + lane];

  // stage 18x18 pixel tile (halo), XOR-swizzled on pixel column
  for (int idx = tid; idx < 18 * 18 * 8; idx += 256) {
    int pix = idx >> 3, ch = idx & 7;
    int r = pix / 18, c = pix % 18;
    int gh = h0 + r - 1, gw = w0 + c - 1;
    int4 v = make_int4(0, 0, 0, 0);
    if (gh >= 0 && gh < H && gw >= 0 && gw < W)
      v = *reinterpret_cast<const int4*>(in + (((size_t)b * H + gh) * W + gw) * 64 + ch * 8);
    int off = ((pix << 7) + (ch << 4)) ^ ((c & 7) << 4);
    *reinterpret_cast<int4*>(lds + off) = v;
  }
  __syncthreads();

  f4 acc[16];
  {
    float bv = bias[(wave << 4) + lm];
    f4 ini = {bv, bv, bv, bv};
#pragma unroll
    for (int f = 0; f < 16; f++) acc[f] = ini;
  }

#pragma unroll
  for (int s = 0; s < 18; s++) {
    int tap = s >> 1;
    int dy = tap / 3, dx = tap % 3;
    int kbyte = (((s & 1) << 5) + (lk << 3)) << 1;  // 16B-aligned
#pragma unroll
    for (int f = 0; f < 16; f++) {
      int lr = f + dy;
      int lc = lm + dx;
      int off = (((lr * 18 + lc) << 7) + kbyte) ^ ((lc & 7) << 4);
      bf8 a = *reinterpret_cast<const bf8*>(lds + off);
      acc[f] = __builtin_amdgcn_mfma_f32_16x16x32_bf16(a, wb[s], acc[f], 0, 0, 0);
    }
  }

  // ---- epilogue: transpose through LDS for coalesced stores ----
  float* ldsf = reinterpret_cast<float*>(lds);
  if (OM == 0) {
    // two halves of 8 pixel-rows each: 8*16 px * 64 co * 4B = 32 KB
    for (int h2 = 0; h2 < 2; h2++) {
      __syncthreads();
#pragma unroll
      for (int fr = 0; fr < 8; fr++) {
        int f = h2 * 8 + fr;
        int co = (wave << 4) + lm;
#pragma unroll
        for (int r = 0; r < 4; r++) {
          int p = (lk << 2) + r;
          ldsf[fr * 1024 + p * 64 + (co ^ ((p & 12) << 2))] = acc[f][r];
        }
      }
      __syncthreads();
#pragma unroll
      for (int i = 0; i < 4; i++) {
        int q = i * 256 + tid;                // 0..1023
        int co8 = q & 7, p = (q >> 3) & 15, fr = q >> 7;
        int cb = (co8 * 8) ^ ((p & 12) << 2);
        f4 v0 = *reinterpret_cast<f4*>(&ldsf[fr * 1024 + p * 64 + cb]);
        f4 v1 = *reinterpret_cast<f4*>(&ldsf[fr * 1024 + p * 64 + cb + 4]);
        float vv[8] = {v0[0], v0[1], v0[2], v0[3], v1[0], v1[1], v1[2], v1[3]};
        union { ushort us[8]; int4 i4; } pk;
#pragma unroll
        for (int j = 0; j < 8; j++) {
          float v = vv[j];
          if (ACT) v = 0.5f * v * (1.f + erff(v * 0.70710678118654752f));
          pk.us[j] = f2bf(v);
        }
        *reinterpret_cast<int4*>(
            outb + (((size_t)b * H + h0 + h2 * 8 + fr) * W + w0 + p) * 64 + co8 * 8) = pk.i4;
      }
    }
  } else {
    // NCHW fp32 + residual; two halves of 32 co each: 32*256*4B = 32 KB
    for (int h2 = 0; h2 < 2; h2++) {
      __syncthreads();
      if ((wave >> 1) == h2) {
        int co32 = ((wave & 1) << 4) + lm;
#pragma unroll
        for (int f = 0; f < 16; f++) {
          int pxl = (f << 4) + (lk << 2);     // pixel linear index (4-aligned)
          int pxs = pxl ^ ((co32 & 7) << 2);  // swizzled store addr (stays 4-aligned)
          *reinterpret_cast<f4*>(&ldsf[co32 * 256 + pxs]) = acc[f];
        }
      }
      __syncthreads();
#pragma unroll
      for (int i = 0; i < 8; i++) {
        int q = i * 256 + tid;                // 0..2047
        int chunk = q & 63, co32 = q >> 6;
        int pq = chunk * 4;                          // UNSWIZZLED pixel base
        int pxs = pq ^ ((co32 & 7) << 2);            // swizzled LDS addr
        f4 v = *reinterpret_cast<f4*>(&ldsf[co32 * 256 + pxs]);  // v[j] = pixel pq+j
        int co = h2 * 32 + co32;
        size_t o = ((size_t)(b * 64 + co)) * HWc +
                   (size_t)(h0 + (pq >> 4)) * W + w0 + (pq & 15);
        float4 rv = *reinterpret_cast<const float4*>(resid + o);
        float4 ov;
        ov.x = v[0] + rv.x; ov.y = v[1] + rv.y; ov.z = v[2] + rv.z; ov.w = v[3] + rv.w;
        *reinterpret_cast<float4*>(outf + o) = ov;
      }
    }
  }
}

// ---------------- depthwise 3x3 + GAP (NHWC bf16 in) ----------------
__global__ __launch_bounds__(256) void dwgap_k(
    const ushort* __restrict__ x1, const float* __restrict__ dww,
    float* __restrict__ pooled) {
  int c = threadIdx.x & 63;
  int q = threadIdx.x >> 6;
  int seg = blockIdx.x * 4 + q;  // 0..1023
  int row = seg >> 2;
  int wbase = (seg & 3) * 64;
  int b = blockIdx.y;
  float wv[9];
#pragma unroll
  for (int t = 0; t < 9; t++) wv[t] = dww[c * 9 + t];

  auto ld = [&](int hh, int ww) -> float {
    if (hh < 0 || hh >= H || ww < 0 || ww >= W) return 0.f;
    return bf2f(x1[(((size_t)b * H + hh) * W + ww) * 64 + c]);
  };
  float v[3][3];
#pragma unroll
  for (int dy = 0; dy < 3; dy++) {
    v[dy][0] = ld(row + dy - 1, wbase - 1);
    v[dy][1] = ld(row + dy - 1, wbase);
  }
  float acc = 0.f;
  for (int i = 0; i < 64; i++) {
    int w = wbase + i;
#pragma unroll
    for (int dy = 0; dy < 3; dy++) v[dy][2] = ld(row + dy - 1, w + 1);
    float s = 0.f;
#pragma unroll
    for (int dy = 0; dy < 3; dy++)
#pragma unroll
      for (int dx = 0; dx < 3; dx++) s += v[dy][dx] * wv[dy * 3 + dx];
    acc += s;
#pragma unroll
    for (int dy = 0; dy < 3; dy++) { v[dy][0] = v[dy][1]; v[dy][1] = v[dy][2]; }
  }
  atomicAdd(&pooled[b * 64 + c], acc);
}

// ---------------- MLP + softmax + blend -> Wm in B-fragment layout ----------------
__global__ void mlp_k(const float* __restrict__ pooled, const float* __restrict__ dwb,
                      const float* __restrict__ c1w, const float* __restrict__ c1b,
                      const float* __restrict__ c2w, const float* __restrict__ c2b,
                      const float* __restrict__ basep, ushort* __restrict__ wmf) {
  int b = blockIdx.x;
  int t = threadIdx.x;  // 64 threads
  __shared__ float pm[64], p1[64], p2[16];
  pm[t] = pooled[b * 64 + t] * (1.f / HWc) + dwb[t];
  __syncthreads();
  float a = c1b[t];
  for (int ci = 0; ci < 64; ci++) a += pm[ci] * c1w[t * 64 + ci];
  p1[t] = fmaxf(a, 0.f);
  __syncthreads();
  if (t < N) {
    float a2 = c2b[t];
    for (int ci = 0; ci < 64; ci++) a2 += p1[ci] * c2w[t * 64 + ci];
    p2[t] = a2;
  }
  __syncthreads();
  float m = -1e30f;
  for (int n = 0; n < N; n++) m = fmaxf(m, p2[n]);
  float e[N], s = 0.f;
  for (int n = 0; n < N; n++) { e[n] = expf(p2[n] - m); s += e[n]; }
  float inv = 1.f / s;
  // wmf[b][(s2*4+cf)*64+lane][j] = Wm[k][l], k = s2*32+(lane>>4)*8+j, l = cf*16+(lane&15)
  for (int idx = t; idx < 4096; idx += 64) {
    int j = idx & 7, lane = (idx >> 3) & 63, cf = (idx >> 9) & 3, s2 = idx >> 11;
    int k = (s2 << 5) + ((lane >> 4) << 3) + j;
    int l = (cf << 4) + (lane & 15);
    float acc = 0.f;
    for (int n = 0; n < N; n++) acc += e[n] * inv * basep[n * 4096 + k * 64 + l];
    wmf[(size_t)b * 4096 + idx] = f2bf(acc);
  }
}

// ---------------- per-pixel 64x64 channel mix via MFMA ----------------
__global__ __launch_bounds__(256, 2) void mix_mfma(
    const ushort* __restrict__ xm, const ushort* __restrict__ wmf,
    ushort* __restrict__ out) {
  __shared__ char lds[16 * 16 * 128];  // 32 KB
  int tid = threadIdx.x;
  int b = blockIdx.z;
  int h0 = blockIdx.y * 16, w0 = blockIdx.x * 16;
  int wave = tid >> 6, lane = tid & 63;
  int lm = lane & 15, lk = lane >> 4;

  const bf8* wf = reinterpret_cast<const bf8*>(wmf + (size_t)b * 4096);
  bf8 wb[2];
#pragma unroll
  for (int s = 0; s < 2; s++) wb[s] = wf[(s * 4 + wave) * 64 + lane];

  for (int idx = tid; idx < 16 * 16 * 8; idx += 256) {
    int pix = idx >> 3, ch = idx & 7;
    int c = pix & 15;
    int4 v = *reinterpret_cast<const int4*>(
        xm + (((size_t)b * H + h0 + (pix >> 4)) * W + w0 + c) * 64 + ch * 8);
    int off = ((pix << 7) + (ch << 4)) ^ ((c & 7) << 4);
    *reinterpret_cast<int4*>(lds + off) = v;
  }
  __syncthreads();

  f4 acc[16];
#pragma unroll
  for (int f = 0; f < 16; f++) acc[f] = (f4){0.f, 0.f, 0.f, 0.f};

#pragma unroll
  for (int s = 0; s < 2; s++) {
    int kbyte = ((s << 5) + (lk << 3)) << 1;
#pragma unroll
    for (int f = 0; f < 16; f++) {
      int off = ((((f << 4) + lm) << 7) + kbyte) ^ ((lm & 7) << 4);
      bf8 a = *reinterpret_cast<const bf8*>(lds + off);
      acc[f] = __builtin_amdgcn_mfma_f32_16x16x32_bf16(a, wb[s], acc[f], 0, 0, 0);
    }
  }

  float* ldsf = reinterpret_cast<float*>(lds);
  for (int h2 = 0; h2 < 2; h2++) {
    __syncthreads();
#pragma unroll
    for (int fr = 0; fr < 8; fr++) {
      int f = h2 * 8 + fr;
      int co = (wave << 4) + lm;
#pragma unroll
      for (int r = 0; r < 4; r++) {
        int p = (lk << 2) + r;
        ldsf[fr * 1024 + p * 64 + (co ^ ((p & 12) << 2))] = acc[f][r];
      }
    }
    __syncthreads();
#pragma unroll
    for (int i = 0; i < 4; i++) {
      int q = i * 256 + tid;
      int co8 = q & 7, p = (q >> 3) & 15, fr = q >> 7;
      int cb = (co8 * 8) ^ ((p & 12) << 2);
      f4 v0 = *reinterpret_cast<f4*>(&ldsf[fr * 1024 + p * 64 + cb]);
      f4 v1 = *reinterpret_cast<f4*>(&ldsf[fr * 1024 + p * 64 + cb + 4]);
      float vv[8] = {v0[0], v0[1], v0[2], v0[3], v1[0], v1[1], v1[2], v1[3]};
      union { ushort us[8]; int4 i4; } pk;
#pragma unroll
      for (int j = 0; j < 8; j++) pk.us[j] = f2bf(vv[j]);
      *reinterpret_cast<int4*>(
          out + (((size_t)b * H + h0 + h2 * 8 + fr) * W + w0 + p) * 64 + co8 * 8) = pk.i4;
    }
  }
}

__global__ void zero_k(float* p, int n) {
  int i = blockIdx.x * 256 + threadIdx.x;
  if (i < n) p[i] = 0.f;
}

extern "C" void kernel_launch(void* const* d_in, const int* in_sizes, int n_in,
                              void* d_out, int out_size, void* d_ws, size_t ws_size,
                              hipStream_t stream) {
  const float* x       = (const float*)d_in[0];
  const float* ln_g    = (const float*)d_in[1];
  const float* ln_b    = (const float*)d_in[2];
  const float* conv3_w = (const float*)d_in[3];
  const float* conv3_b = (const float*)d_in[4];
  const float* dw_w    = (const float*)d_in[5];
  const float* dw_b    = (const float*)d_in[6];
  const float* c1_w    = (const float*)d_in[7];
  const float* c1_b    = (const float*)d_in[8];
  const float* c2_w    = (const float*)d_in[9];
  const float* c2_b    = (const float*)d_in[10];
  const float* basep   = (const float*)d_in[11];
  const float* up_w    = (const float*)d_in[12];
  const float* up_b    = (const float*)d_in[13];
  const float* down_w  = (const float*)d_in[14];
  const float* down_b  = (const float*)d_in[15];
  float* out = (float*)d_out;

  char* wsb = (char*)d_ws;
  size_t big = (size_t)B * HWc * 64 * sizeof(ushort);  // 67,108,864
  ushort* bufA   = (ushort*)wsb;
  ushort* bufB   = (ushort*)(wsb + big);
  ushort* wfrags = (ushort*)(wsb + 2 * big);
  ushort* wmfrag = (ushort*)(wsb + 2 * big + 3 * 36864 * 2);
  float*  pooled = (float*)(wsb + 2 * big + 3 * 36864 * 2 + 8 * 4096 * 2);

  prep_w<<<54, 256, 0, stream>>>(conv3_w, up_w, down_w, wfrags);
  zero_k<<<2, 256, 0, stream>>>(pooled, B * C);
  // 1. LN: x -> bufA (NHWC bf16)
  ln_k<<<dim3(HWc / 256, B), 256, 0, stream>>>(x, ln_g, ln_b, bufA);
  // 2. conv3 + GELU: bufA -> bufB
  conv_mfma<1, 0><<<dim3(16, 16, B), 256, 0, stream>>>(
      bufA, wfrags + 0 * 36864, conv3_b, nullptr, bufB, nullptr);
  // 3. dw + GAP: bufB -> pooled
  dwgap_k<<<dim3(256, B), 256, 0, stream>>>(bufB, dw_w, pooled);
  // 4. MLP + blend: pooled -> wmfrag
  mlp_k<<<B, 64, 0, stream>>>(pooled, dw_b, c1_w, c1_b, c2_w, c2_b, basep, wmfrag);
  // 5. up conv: bufB -> bufA (xm)
  conv_mfma<0, 0><<<dim3(16, 16, B), 256, 0, stream>>>(
      bufB, wfrags + 1 * 36864, up_b, nullptr, bufA, nullptr);
  // 6. mix: bufA -> bufB (xm2)
  mix_mfma<<<dim3(16, 16, B), 256, 0, stream>>>(bufA, wmfrag, bufB);
  // 7. down conv + residual: bufB -> out (NCHW fp32)
  conv_mfma<0, 1><<<dim3(16, 16, B), 256, 0, stream>>>(
      bufB, wfrags + 2 * 36864, down_b, x, nullptr, out);
}

// Round 5
// 436.184 us; speedup vs baseline: 3.1832x; 3.1832x over previous
//
#include <hip/hip_runtime.h>
#include <math.h>

constexpr int B = 8, C = 64, H = 256, W = 256, HWc = H * W, N = 10;

typedef short bf8 __attribute__((ext_vector_type(8)));    // 8 x bf16 (4 VGPR)
typedef float f4  __attribute__((ext_vector_type(4)));    // MFMA accum
typedef unsigned short ushort;

__device__ __forceinline__ ushort f2bf(float f) {
  unsigned u = __builtin_bit_cast(unsigned, f);
  unsigned r = (u + 0x7fffu + ((u >> 16) & 1u)) >> 16;
  return (ushort)r;
}
__device__ __forceinline__ float bf2f(ushort h) {
  unsigned u = ((unsigned)h) << 16;
  return __builtin_bit_cast(float, u);
}

// ---------------- LayerNorm: NCHW fp32 -> NHWC bf16 ----------------
__global__ __launch_bounds__(256) void ln_k(
    const float* __restrict__ x, const float* __restrict__ g,
    const float* __restrict__ bt, ushort* __restrict__ xn) {
  int pix = blockIdx.x * 256 + threadIdx.x;
  int b = blockIdx.y;
  const float* xp = x + (size_t)b * C * HWc + pix;
  float v[64];
  float s = 0.f, s2 = 0.f;
#pragma unroll
  for (int c = 0; c < 64; c++) {
    v[c] = xp[(size_t)c * HWc];
    s += v[c]; s2 += v[c] * v[c];
  }
  float mu = s * (1.f / 64);
  float var = s2 * (1.f / 64) - mu * mu;
  float rstd = rsqrtf(var + 1e-5f);
  ushort* op = xn + ((size_t)b * HWc + pix) * 64;
#pragma unroll
  for (int ch = 0; ch < 8; ch++) {
    union { ushort us[8]; int4 v4; } pk;
#pragma unroll
    for (int j = 0; j < 8; j++) {
      int c = ch * 8 + j;
      pk.us[j] = f2bf((v[c] - mu) * rstd * g[c] + bt[c]);
    }
    *reinterpret_cast<int4*>(op + ch * 8) = pk.v4;
  }
}

// ---------------- weight prep: OIHW fp32 -> MFMA fragment layout bf16 ----------------
// frags[conv][((s*4+cf)*64+lane)*8+j] = w[co][ci][tap]
//   co = cf*16 + (lane&15); tap = s>>1; ci = (s&1)*32 + (lane>>4)*8 + j
__global__ void prep_w(const float* __restrict__ w3, const float* __restrict__ wu,
                       const float* __restrict__ wd, ushort* __restrict__ frags) {
  int idx = blockIdx.x * 256 + threadIdx.x;
  if (idx >= 3 * 4608) return;
  int conv = idx / 4608, r = idx % 4608;
  int s = r >> 8, cf = (r >> 6) & 3, lane = r & 63;
  const float* w = (conv == 0) ? w3 : (conv == 1) ? wu : wd;
  int co = (cf << 4) + (lane & 15);
  int tap = s >> 1;
  ushort* o = frags + conv * 36864 + ((size_t)r) * 8;
#pragma unroll
  for (int j = 0; j < 8; j++) {
    int ci = ((s & 1) << 5) + ((lane >> 4) << 3) + j;
    o[j] = f2bf(w[(co * 64 + ci) * 9 + tap]);
  }
}

// ---------------- MFMA implicit-GEMM 3x3 conv ----------------
// in: NHWC bf16. OM=0: out NHWC bf16 (+GELU if ACT). OM=1: out NCHW fp32 + residual.
// Wave w owns co group [16w,16w+16). K-loop grouped by (ci-half, dx):
// A rows 0..17 read once per group and reused across the 3 dy taps.
template <int ACT, int OM>
__global__ __launch_bounds__(256, 2) void conv_mfma(
    const ushort* __restrict__ in, const ushort* __restrict__ wfrag,
    const float* __restrict__ bias, const float* __restrict__ resid,
    ushort* __restrict__ outb, float* __restrict__ outf) {
  __shared__ char lds[18 * 18 * 128];  // 41472 B (epilogue reuses 32 KB of it)
  int tid = threadIdx.x;
  int b = blockIdx.z;
  int h0 = blockIdx.y * 16, w0 = blockIdx.x * 16;
  int wave = tid >> 6, lane = tid & 63;
  int lm = lane & 15, lk = lane >> 4;

  const bf8* wf = reinterpret_cast<const bf8*>(wfrag);

  // stage 18x18 pixel tile (halo), XOR-swizzled on pixel column
  for (int idx = tid; idx < 18 * 18 * 8; idx += 256) {
    int pix = idx >> 3, ch = idx & 7;
    int r = pix / 18, c = pix % 18;
    int gh = h0 + r - 1, gw = w0 + c - 1;
    int4 v = make_int4(0, 0, 0, 0);
    if (gh >= 0 && gh < H && gw >= 0 && gw < W)
      v = *reinterpret_cast<const int4*>(in + (((size_t)b * H + gh) * W + gw) * 64 + ch * 8);
    int off = ((pix << 7) + (ch << 4)) ^ ((c & 7) << 4);
    *reinterpret_cast<int4*>(lds + off) = v;
  }
  __syncthreads();

  f4 acc[16];
  {
    float bv = bias[(wave << 4) + lm];
    f4 ini = {bv, bv, bv, bv};
#pragma unroll
    for (int f = 0; f < 16; f++) acc[f] = ini;
  }

#pragma unroll
  for (int ch = 0; ch < 2; ch++) {
#pragma unroll
    for (int dx = 0; dx < 3; dx++) {
      // B-frags for the 3 dy taps of this (ci-half, dx) group
      bf8 wb3[3];
#pragma unroll
      for (int dy = 0; dy < 3; dy++) {
        int s = ((dy * 3 + dx) << 1) | ch;   // orig step index for prep_w layout
        wb3[dy] = wf[(s * 4 + wave) * 64 + lane];
      }
      int lc = lm + dx;
      int kbyte = (ch << 6) + (lk << 4);
      int swz = (lc & 7) << 4;
      // A fragments: tile rows 0..17 at pixel column lc, ci-half ch
      bf8 a[18];
#pragma unroll
      for (int r = 0; r < 18; r++) {
        int off = (((r * 18 + lc) << 7) + kbyte) ^ swz;
        a[r] = *reinterpret_cast<const bf8*>(lds + off);
      }
#pragma unroll
      for (int dy = 0; dy < 3; dy++)
#pragma unroll
        for (int f = 0; f < 16; f++)
          acc[f] = __builtin_amdgcn_mfma_f32_16x16x32_bf16(a[f + dy], wb3[dy], acc[f], 0, 0, 0);
    }
  }

  // ---- epilogue: transpose through LDS for coalesced stores ----
  float* ldsf = reinterpret_cast<float*>(lds);
  if (OM == 0) {
    // two halves of 8 pixel-rows each: 8*16 px * 64 co * 4B = 32 KB
    for (int h2 = 0; h2 < 2; h2++) {
      __syncthreads();
#pragma unroll
      for (int fr = 0; fr < 8; fr++) {
        int f = h2 * 8 + fr;
        int co = (wave << 4) + lm;
#pragma unroll
        for (int r = 0; r < 4; r++) {
          int p = (lk << 2) + r;
          ldsf[fr * 1024 + p * 64 + (co ^ ((p & 12) << 2))] = acc[f][r];
        }
      }
      __syncthreads();
#pragma unroll
      for (int i = 0; i < 4; i++) {
        int q = i * 256 + tid;                // 0..1023
        int co8 = q & 7, p = (q >> 3) & 15, fr = q >> 7;
        int cb = (co8 * 8) ^ ((p & 12) << 2);
        f4 v0 = *reinterpret_cast<f4*>(&ldsf[fr * 1024 + p * 64 + cb]);
        f4 v1 = *reinterpret_cast<f4*>(&ldsf[fr * 1024 + p * 64 + cb + 4]);
        float vv[8] = {v0[0], v0[1], v0[2], v0[3], v1[0], v1[1], v1[2], v1[3]};
        union { ushort us[8]; int4 i4; } pk;
#pragma unroll
        for (int j = 0; j < 8; j++) {
          float v = vv[j];
          if (ACT) v = 0.5f * v * (1.f + erff(v * 0.70710678118654752f));
          pk.us[j] = f2bf(v);
        }
        *reinterpret_cast<int4*>(
            outb + (((size_t)b * H + h0 + h2 * 8 + fr) * W + w0 + p) * 64 + co8 * 8) = pk.i4;
      }
    }
  } else {
    // NCHW fp32 + residual; two halves of 32 co each: 32*256*4B = 32 KB
    for (int h2 = 0; h2 < 2; h2++) {
      __syncthreads();
      if ((wave >> 1) == h2) {
        int co32 = ((wave & 1) << 4) + lm;
#pragma unroll
        for (int f = 0; f < 16; f++) {
          int pxl = (f << 4) + (lk << 2);     // pixel linear index (4-aligned)
          int pxs = pxl ^ ((co32 & 7) << 2);  // swizzled store addr (stays 4-aligned)
          *reinterpret_cast<f4*>(&ldsf[co32 * 256 + pxs]) = acc[f];
        }
      }
      __syncthreads();
#pragma unroll
      for (int i = 0; i < 8; i++) {
        int q = i * 256 + tid;                // 0..2047
        int chunk = q & 63, co32 = q >> 6;
        int pq = chunk * 4;                          // UNSWIZZLED pixel base
        int pxs = pq ^ ((co32 & 7) << 2);            // swizzled LDS addr
        f4 v = *reinterpret_cast<f4*>(&ldsf[co32 * 256 + pxs]);  // v[j] = pixel pq+j
        int co = h2 * 32 + co32;
        size_t o = ((size_t)(b * 64 + co)) * HWc +
                   (size_t)(h0 + (pq >> 4)) * W + w0 + (pq & 15);
        float4 rv = *reinterpret_cast<const float4*>(resid + o);
        float4 ov;
        ov.x = v[0] + rv.x; ov.y = v[1] + rv.y; ov.z = v[2] + rv.z; ov.w = v[3] + rv.w;
        *reinterpret_cast<float4*>(outf + o) = ov;
      }
    }
  }
}

// ---------------- depthwise 3x3 + GAP (NHWC bf16 in) ----------------
__global__ __launch_bounds__(256) void dwgap_k(
    const ushort* __restrict__ x1, const float* __restrict__ dww,
    float* __restrict__ pooled) {
  int c = threadIdx.x & 63;
  int q = threadIdx.x >> 6;
  int seg = blockIdx.x * 4 + q;  // 0..1023
  int row = seg >> 2;
  int wbase = (seg & 3) * 64;
  int b = blockIdx.y;
  float wv[9];
#pragma unroll
  for (int t = 0; t < 9; t++) wv[t] = dww[c * 9 + t];

  auto ld = [&](int hh, int ww) -> float {
    if (hh < 0 || hh >= H || ww < 0 || ww >= W) return 0.f;
    return bf2f(x1[(((size_t)b * H + hh) * W + ww) * 64 + c]);
  };
  float v[3][3];
#pragma unroll
  for (int dy = 0; dy < 3; dy++) {
    v[dy][0] = ld(row + dy - 1, wbase - 1);
    v[dy][1] = ld(row + dy - 1, wbase);
  }
  float acc = 0.f;
  for (int i = 0; i < 64; i++) {
    int w = wbase + i;
#pragma unroll
    for (int dy = 0; dy < 3; dy++) v[dy][2] = ld(row + dy - 1, w + 1);
    float s = 0.f;
#pragma unroll
    for (int dy = 0; dy < 3; dy++)
#pragma unroll
      for (int dx = 0; dx < 3; dx++) s += v[dy][dx] * wv[dy * 3 + dx];
    acc += s;
#pragma unroll
    for (int dy = 0; dy < 3; dy++) { v[dy][0] = v[dy][1]; v[dy][1] = v[dy][2]; }
  }
  atomicAdd(&pooled[b * 64 + c], acc);
}

// ---------------- MLP + softmax + blend -> Wm in B-fragment layout ----------------
__global__ void mlp_k(const float* __restrict__ pooled, const float* __restrict__ dwb,
                      const float* __restrict__ c1w, const float* __restrict__ c1b,
                      const float* __restrict__ c2w, const float* __restrict__ c2b,
                      const float* __restrict__ basep, ushort* __restrict__ wmf) {
  int b = blockIdx.x;
  int t = threadIdx.x;  // 64 threads
  __shared__ float pm[64], p1[64], p2[16];
  pm[t] = pooled[b * 64 + t] * (1.f / HWc) + dwb[t];
  __syncthreads();
  float a = c1b[t];
  for (int ci = 0; ci < 64; ci++) a += pm[ci] * c1w[t * 64 + ci];
  p1[t] = fmaxf(a, 0.f);
  __syncthreads();
  if (t < N) {
    float a2 = c2b[t];
    for (int ci = 0; ci < 64; ci++) a2 += p1[ci] * c2w[t * 64 + ci];
    p2[t] = a2;
  }
  __syncthreads();
  float m = -1e30f;
  for (int n = 0; n < N; n++) m = fmaxf(m, p2[n]);
  float e[N], s = 0.f;
  for (int n = 0; n < N; n++) { e[n] = expf(p2[n] - m); s += e[n]; }
  float inv = 1.f / s;
  // wmf[b][(s2*4+cf)*64+lane][j] = Wm[k][l], k = s2*32+(lane>>4)*8+j, l = cf*16+(lane&15)
  for (int idx = t; idx < 4096; idx += 64) {
    int j = idx & 7, lane = (idx >> 3) & 63, cf = (idx >> 9) & 3, s2 = idx >> 11;
    int k = (s2 << 5) + ((lane >> 4) << 3) + j;
    int l = (cf << 4) + (lane & 15);
    float acc = 0.f;
    for (int n = 0; n < N; n++) acc += e[n] * inv * basep[n * 4096 + k * 64 + l];
    wmf[(size_t)b * 4096 + idx] = f2bf(acc);
  }
}

// ---------------- per-pixel 64x64 channel mix via MFMA ----------------
__global__ __launch_bounds__(256, 2) void mix_mfma(
    const ushort* __restrict__ xm, const ushort* __restrict__ wmf,
    ushort* __restrict__ out) {
  __shared__ char lds[16 * 16 * 128];  // 32 KB
  int tid = threadIdx.x;
  int b = blockIdx.z;
  int h0 = blockIdx.y * 16, w0 = blockIdx.x * 16;
  int wave = tid >> 6, lane = tid & 63;
  int lm = lane & 15, lk = lane >> 4;

  const bf8* wf = reinterpret_cast<const bf8*>(wmf + (size_t)b * 4096);
  bf8 wb[2];
#pragma unroll
  for (int s = 0; s < 2; s++) wb[s] = wf[(s * 4 + wave) * 64 + lane];

  for (int idx = tid; idx < 16 * 16 * 8; idx += 256) {
    int pix = idx >> 3, ch = idx & 7;
    int c = pix & 15;
    int4 v = *reinterpret_cast<const int4*>(
        xm + (((size_t)b * H + h0 + (pix >> 4)) * W + w0 + c) * 64 + ch * 8);
    int off = ((pix << 7) + (ch << 4)) ^ ((c & 7) << 4);
    *reinterpret_cast<int4*>(lds + off) = v;
  }
  __syncthreads();

  f4 acc[16];
#pragma unroll
  for (int f = 0; f < 16; f++) acc[f] = (f4){0.f, 0.f, 0.f, 0.f};

#pragma unroll
  for (int s = 0; s < 2; s++) {
    int kbyte = ((s << 5) + (lk << 3)) << 1;
#pragma unroll
    for (int f = 0; f < 16; f++) {
      int off = ((((f << 4) + lm) << 7) + kbyte) ^ ((lm & 7) << 4);
      bf8 a = *reinterpret_cast<const bf8*>(lds + off);
      acc[f] = __builtin_amdgcn_mfma_f32_16x16x32_bf16(a, wb[s], acc[f], 0, 0, 0);
    }
  }

  float* ldsf = reinterpret_cast<float*>(lds);
  for (int h2 = 0; h2 < 2; h2++) {
    __syncthreads();
#pragma unroll
    for (int fr = 0; fr < 8; fr++) {
      int f = h2 * 8 + fr;
      int co = (wave << 4) + lm;
#pragma unroll
      for (int r = 0; r < 4; r++) {
        int p = (lk << 2) + r;
        ldsf[fr * 1024 + p * 64 + (co ^ ((p & 12) << 2))] = acc[f][r];
      }
    }
    __syncthreads();
#pragma unroll
    for (int i = 0; i < 4; i++) {
      int q = i * 256 + tid;
      int co8 = q & 7, p = (q >> 3) & 15, fr = q >> 7;
      int cb = (co8 * 8) ^ ((p & 12) << 2);
      f4 v0 = *reinterpret_cast<f4*>(&ldsf[fr * 1024 + p * 64 + cb]);
      f4 v1 = *reinterpret_cast<f4*>(&ldsf[fr * 1024 + p * 64 + cb + 4]);
      float vv[8] = {v0[0], v0[1], v0[2], v0[3], v1[0], v1[1], v1[2], v1[3]};
      union { ushort us[8]; int4 i4; } pk;
#pragma unroll
      for (int j = 0; j < 8; j++) pk.us[j] = f2bf(vv[j]);
      *reinterpret_cast<int4*>(
          out + (((size_t)b * H + h0 + h2 * 8 + fr) * W + w0 + p) * 64 + co8 * 8) = pk.i4;
    }
  }
}

__global__ void zero_k(float* p, int n) {
  int i = blockIdx.x * 256 + threadIdx.x;
  if (i < n) p[i] = 0.f;
}

extern "C" void kernel_launch(void* const* d_in, const int* in_sizes, int n_in,
                              void* d_out, int out_size, void* d_ws, size_t ws_size,
                              hipStream_t stream) {
  const float* x       = (const float*)d_in[0];
  const float* ln_g    = (const float*)d_in[1];
  const float* ln_b    = (const float*)d_in[2];
  const float* conv3_w = (const float*)d_in[3];
  const float* conv3_b = (const float*)d_in[4];
  const float* dw_w    = (const float*)d_in[5];
  const float* dw_b    = (const float*)d_in[6];
  const float* c1_w    = (const float*)d_in[7];
  const float* c1_b    = (const float*)d_in[8];
  const float* c2_w    = (const float*)d_in[9];
  const float* c2_b    = (const float*)d_in[10];
  const float* basep   = (const float*)d_in[11];
  const float* up_w    = (const float*)d_in[12];
  const float* up_b    = (const float*)d_in[13];
  const float* down_w  = (const float*)d_in[14];
  const float* down_b  = (const float*)d_in[15];
  float* out = (float*)d_out;

  char* wsb = (char*)d_ws;
  size_t big = (size_t)B * HWc * 64 * sizeof(ushort);  // 67,108,864
  ushort* bufA   = (ushort*)wsb;
  ushort* bufB   = (ushort*)(wsb + big);
  ushort* wfrags = (ushort*)(wsb + 2 * big);
  ushort* wmfrag = (ushort*)(wsb + 2 * big + 3 * 36864 * 2);
  float*  pooled = (float*)(wsb + 2 * big + 3 * 36864 * 2 + 8 * 4096 * 2);

  prep_w<<<54, 256, 0, stream>>>(conv3_w, up_w, down_w, wfrags);
  zero_k<<<2, 256, 0, stream>>>(pooled, B * C);
  // 1. LN: x -> bufA (NHWC bf16)
  ln_k<<<dim3(HWc / 256, B), 256, 0, stream>>>(x, ln_g, ln_b, bufA);
  // 2. conv3 + GELU: bufA -> bufB
  conv_mfma<1, 0><<<dim3(16, 16, B), 256, 0, stream>>>(
      bufA, wfrags + 0 * 36864, conv3_b, nullptr, bufB, nullptr);
  // 3. dw + GAP: bufB -> pooled
  dwgap_k<<<dim3(256, B), 256, 0, stream>>>(bufB, dw_w, pooled);
  // 4. MLP + blend: pooled -> wmfrag
  mlp_k<<<B, 64, 0, stream>>>(pooled, dw_b, c1_w, c1_b, c2_w, c2_b, basep, wmfrag);
  // 5. up conv: bufB -> bufA (xm)
  conv_mfma<0, 0><<<dim3(16, 16, B), 256, 0, stream>>>(
      bufB, wfrags + 1 * 36864, up_b, nullptr, bufA, nullptr);
  // 6. mix: bufA -> bufB (xm2)
  mix_mfma<<<dim3(16, 16, B), 256, 0, stream>>>(bufA, wmfrag, bufB);
  // 7. down conv + residual: bufB -> out (NCHW fp32)
  conv_mfma<0, 1><<<dim3(16, 16, B), 256, 0, stream>>>(
      bufB, wfrags + 2 * 36864, down_b, x, nullptr, out);
}